// Round 1
// baseline (104.042 us; speedup 1.0000x reference)
//
#include <hip/hip_runtime.h>

// Bahdanau attention, fused. Shapes:
//   query [8][400][256], y [8][400][256], Wq_w [128][256], Wq_b [128],
//   Wy_w [128][256], Wy_b [128], v_w [1][128], v_b [1] (dropped: softmax-invariant),
//   n_wins_y [8] int32. out [8][400][256] f32.
// ws: qp' [3200][128] f32 + yp' [3200][128] f32 = 3.28 MB (prescaled by 2*log2e).

#define LOG2E 1.4426950408889634f
#define TANH_SCALE 2.8853900817779268f  // 2*log2(e)

constexpr int TQn = 400, TYn = 400, AD = 128, DD = 256;
constexpr int QT = 8;              // queries per fused block
constexpr int QBLOCKS = TQn / QT;  // 50
constexpr int YT = 64;             // yp tile rows (score phase)
constexpr int YPAD = 132;          // padded yp row stride (floats)
constexpr int AT = 32;             // y tile rows (apply phase)

// ---------------- projection: qp' = (query@WqT + bq)*S ; yp' likewise ----------
__global__ __launch_bounds__(128) void proj_kernel(
    const float* __restrict__ qin, const float* __restrict__ yin,
    const float* __restrict__ Wq, const float* __restrict__ bq,
    const float* __restrict__ Wy, const float* __restrict__ by,
    float* __restrict__ qp, float* __restrict__ yp)
{
    // 800 blocks: [0,400) -> q rows, [400,800) -> y rows. 8 rows/block, 1 thread per a.
    int blk = blockIdx.x;
    bool is_q = blk < 400;
    int row0 = (is_q ? blk : blk - 400) * 8;
    const float* in  = (is_q ? qin : yin) + (size_t)row0 * DD;
    const float* W   = is_q ? Wq : Wy;
    const float* bias = is_q ? bq : by;
    float* outp = (is_q ? qp : yp) + (size_t)row0 * AD;

    __shared__ float lin[8 * DD];
    {
        const float4* in4 = reinterpret_cast<const float4*>(in);
        float4* l4 = reinterpret_cast<float4*>(lin);
        for (int j = threadIdx.x; j < 8 * DD / 4; j += 128) l4[j] = in4[j];
    }
    __syncthreads();

    int a = threadIdx.x;  // 0..127
    float acc[8] = {0.f,0.f,0.f,0.f,0.f,0.f,0.f,0.f};
    const float4* w4p = reinterpret_cast<const float4*>(W + (size_t)a * DD);
    const float4* l4 = reinterpret_cast<const float4*>(lin);
    for (int d4 = 0; d4 < DD / 4; ++d4) {
        float4 w4 = w4p[d4];
        #pragma unroll
        for (int r = 0; r < 8; ++r) {
            float4 v = l4[r * (DD/4) + d4];  // broadcast
            acc[r] = fmaf(w4.x, v.x, acc[r]);
            acc[r] = fmaf(w4.y, v.y, acc[r]);
            acc[r] = fmaf(w4.z, v.z, acc[r]);
            acc[r] = fmaf(w4.w, v.w, acc[r]);
        }
    }
    float bb = bias[a];
    #pragma unroll
    for (int r = 0; r < 8; ++r)
        outp[(size_t)r * AD + a] = (acc[r] + bb) * TANH_SCALE;
}

// ---------------- fused scores -> masked softmax -> att @ y --------------------
__global__ __launch_bounds__(256) void fused_kernel(
    const float* __restrict__ y,    // [B][TY][DD]
    const float* __restrict__ qp,   // [B*TQ][AD] prescaled
    const float* __restrict__ yp,   // [B*TY][AD] prescaled
    const float* __restrict__ vw,   // [AD]
    const int*  __restrict__ nwins, // [B]
    float* __restrict__ out)        // [B][TQ][DD]
{
    __shared__ float s_qp[QT * AD];       // 4 KB
    __shared__ float s_v[AD];             // 0.5 KB
    __shared__ float s_p[QT][TYn];        // 12.8 KB
    __shared__ float s_buf[YT * YPAD];    // 33.8 KB; reused as y tile [AT][DD]

    const int b  = blockIdx.x / QBLOCKS;
    const int q0 = (blockIdx.x % QBLOCKS) * QT;
    const int tid = threadIdx.x;
    const int n = nwins[b];
    const float NEG_INF = -__builtin_inff();

    // stage qp tile + v
    {
        const float4* src = reinterpret_cast<const float4*>(qp + (size_t)(b * TQn + q0) * AD);
        float4* dst = reinterpret_cast<float4*>(s_qp);
        for (int j = tid; j < QT * AD / 4; j += 256) dst[j] = src[j];
        if (tid < AD / 4)
            reinterpret_cast<float4*>(s_v)[tid] = reinterpret_cast<const float4*>(vw)[tid];
    }

    const int q = tid >> 5;   // 0..7 local query
    const int tl = tid & 31;  // t-lane

    float sc[14];
    #pragma unroll
    for (int j = 0; j < 14; ++j) sc[j] = NEG_INF;

    const float4* ypb = reinterpret_cast<const float4*>(yp + (size_t)b * TYn * AD);

    // ---- score phase: 7 tiles of up to 64 t ----
    for (int i = 0; i < 7; ++i) {
        int t0 = i * YT;
        int tt = min(YT, TYn - t0);  // 64,64,...,16
        __syncthreads();             // prior consumers of s_buf done (also covers qp/v staging on i==0)
        for (int j = tid; j < tt * (AD / 4); j += 256) {
            int tloc = j >> 5, a4 = j & 31;
            float4 v4 = ypb[(size_t)(t0 + tloc) * (AD / 4) + a4];
            *reinterpret_cast<float4*>(&s_buf[tloc * YPAD + a4 * 4]) = v4;
        }
        __syncthreads();
        #pragma unroll
        for (int k = 0; k < 2; ++k) {
            int tloc = tl + 32 * k;
            if (tloc < tt) {
                float acc = 0.f;
                const float* yprow = &s_buf[tloc * YPAD];
                const float* qprow = &s_qp[q * AD];
                #pragma unroll 8
                for (int a4 = 0; a4 < AD / 4; ++a4) {
                    float4 yv = *reinterpret_cast<const float4*>(&yprow[a4 * 4]);
                    float4 qv = *reinterpret_cast<const float4*>(&qprow[a4 * 4]);
                    float4 vv = *reinterpret_cast<const float4*>(&s_v[a4 * 4]);
                    float e, r;
                    e = __builtin_amdgcn_exp2f(qv.x + yv.x); r = __builtin_amdgcn_rcpf(e + 1.f);
                    acc = fmaf(vv.x, fmaf(-2.f, r, 1.f), acc);
                    e = __builtin_amdgcn_exp2f(qv.y + yv.y); r = __builtin_amdgcn_rcpf(e + 1.f);
                    acc = fmaf(vv.y, fmaf(-2.f, r, 1.f), acc);
                    e = __builtin_amdgcn_exp2f(qv.z + yv.z); r = __builtin_amdgcn_rcpf(e + 1.f);
                    acc = fmaf(vv.z, fmaf(-2.f, r, 1.f), acc);
                    e = __builtin_amdgcn_exp2f(qv.w + yv.w); r = __builtin_amdgcn_rcpf(e + 1.f);
                    acc = fmaf(vv.w, fmaf(-2.f, r, 1.f), acc);
                }
                sc[i * 2 + k] = acc;
            }
        }
    }

    // ---- mask + softmax over t (per q = 32-lane group; xor<32 stays in group) ----
    #pragma unroll
    for (int j = 0; j < 14; ++j) {
        int t = (j >> 1) * YT + (j & 1) * 32 + tl;
        if (t >= n) sc[j] = NEG_INF;  // also leaves t>=400 entries at -inf
    }
    float m = sc[0];
    #pragma unroll
    for (int j = 1; j < 14; ++j) m = fmaxf(m, sc[j]);
    #pragma unroll
    for (int off = 16; off >= 1; off >>= 1) m = fmaxf(m, __shfl_xor(m, off, 64));
    float l = 0.f;
    #pragma unroll
    for (int j = 0; j < 14; ++j) {
        float pv = __builtin_amdgcn_exp2f((sc[j] - m) * LOG2E);  // exp2(-inf)=0 for masked
        sc[j] = pv;
        l += pv;
    }
    #pragma unroll
    for (int off = 16; off >= 1; off >>= 1) l += __shfl_xor(l, off, 64);
    float inv = 1.0f / l;
    #pragma unroll
    for (int j = 0; j < 14; ++j) {
        int t = (j >> 1) * YT + (j & 1) * 32 + tl;
        if (t < TYn) s_p[q][t] = sc[j] * inv;
    }

    // ---- apply phase: out[q][d] = sum_t p[t] * y[t][d], tiles of 32 t ----
    const int dl = tl;  // float4 column: d = dl*4 and 128 + dl*4
    float4 a0 = {0.f,0.f,0.f,0.f}, a1 = {0.f,0.f,0.f,0.f};
    const float4* yb = reinterpret_cast<const float4*>(y + (size_t)b * TYn * DD);
    for (int tile = 0; tile < (TYn + AT - 1) / AT; ++tile) {
        int t0 = tile * AT;
        if (t0 >= n) break;  // uniform: p==0 beyond n
        int tt = min(AT, TYn - t0);
        __syncthreads();     // prior consumers of s_buf / s_p stores visible
        for (int j = tid; j < tt * (DD / 4); j += 256) {
            int tloc = j >> 6, d4 = j & 63;
            reinterpret_cast<float4*>(s_buf)[tloc * (DD / 4) + d4] =
                yb[(size_t)(t0 + tloc) * (DD / 4) + d4];
        }
        __syncthreads();
        int tmax = min(tt, n - t0);
        for (int ttl = 0; ttl < tmax; ++ttl) {
            float pt = s_p[q][t0 + ttl];  // broadcast
            const float4* row = reinterpret_cast<const float4*>(&s_buf[ttl * DD]);
            float4 ya = row[dl];
            float4 yc = row[32 + dl];
            a0.x = fmaf(pt, ya.x, a0.x); a0.y = fmaf(pt, ya.y, a0.y);
            a0.z = fmaf(pt, ya.z, a0.z); a0.w = fmaf(pt, ya.w, a0.w);
            a1.x = fmaf(pt, yc.x, a1.x); a1.y = fmaf(pt, yc.y, a1.y);
            a1.z = fmaf(pt, yc.z, a1.z); a1.w = fmaf(pt, yc.w, a1.w);
        }
    }
    float4* op = reinterpret_cast<float4*>(out + (size_t)(b * TQn + q0 + q) * DD);
    op[dl] = a0;
    op[32 + dl] = a1;
}

extern "C" void kernel_launch(void* const* d_in, const int* in_sizes, int n_in,
                              void* d_out, int out_size, void* d_ws, size_t ws_size,
                              hipStream_t stream) {
    const float* query = (const float*)d_in[0];
    const float* y     = (const float*)d_in[1];
    const float* Wq_w  = (const float*)d_in[2];
    const float* Wq_b  = (const float*)d_in[3];
    const float* Wy_w  = (const float*)d_in[4];
    const float* Wy_b  = (const float*)d_in[5];
    const float* v_w   = (const float*)d_in[6];
    // d_in[7] = v_b: softmax-invariant, dropped.
    const int* nw      = (const int*)d_in[8];
    float* out = (float*)d_out;

    float* qp = (float*)d_ws;                    // [3200][128]
    float* yp = qp + (size_t)8 * 400 * 128;      // [3200][128]

    proj_kernel<<<800, 128, 0, stream>>>(query, y, Wq_w, Wq_b, Wy_w, Wy_b, qp, yp);
    fused_kernel<<<8 * QBLOCKS, 256, 0, stream>>>(y, qp, yp, v_w, nw, out);
}